// Round 7
// baseline (342.449 us; speedup 1.0000x reference)
//
#include <hip/hip_runtime.h>
#include <stdint.h>

typedef unsigned int u32;
typedef unsigned short u16;
typedef __bf16 bf16x8 __attribute__((ext_vector_type(8)));
typedef float floatx4 __attribute__((ext_vector_type(4)));
typedef u32 u32x4 __attribute__((ext_vector_type(4)));
typedef float floatx4f __attribute__((ext_vector_type(4)));
typedef float floatx4v __attribute__((ext_vector_type(4)));
typedef float floatx16 __attribute__((ext_vector_type(16)));
typedef float floatx4b __attribute__((ext_vector_type(4)));
typedef float floatx4c __attribute__((ext_vector_type(4)));
typedef float floatx4d __attribute__((ext_vector_type(4)));
typedef float floatx4e __attribute__((ext_vector_type(4)));

__device__ __forceinline__ u16 f2b(float f) {
    u32 u = __builtin_bit_cast(u32, f);
    u32 r = u + 0x7FFFu + ((u >> 16) & 1u);
    return (u16)(r >> 16);
}
__device__ __forceinline__ float lo2f(u32 u) { return __builtin_bit_cast(float, u << 16); }
__device__ __forceinline__ float hi2f(u32 u) { return __builtin_bit_cast(float, u & 0xFFFF0000u); }

// ---------------- wave-uniform self-detection ----------------
__device__ __forceinline__ void self_detect(const int* ei, const u32* xw, int& is64, int& isbf) {
    int lane = threadIdx.x & 63;
    int v = ei ? ei[2 * lane + 1] : 0;
    unsigned long long b1 = __ballot(v == 0);
    u32 w = xw ? xw[lane] : 0;
    u32 e = (w >> 7) & 0xFF;
    int plaus = (e == 0) || (e >= 90 && e <= 140);
    unsigned long long b2 = __ballot(plaus);
    is64 = (b1 == ~0ULL) ? 1 : 0;
    isbf = (b2 == ~0ULL) ? 1 : 0;
}

__device__ __forceinline__ float load_f(const void* __restrict__ p, int isbf, size_t i) {
    if (isbf) {
        u16 s = ((const u16*)p)[i];
        return __builtin_bit_cast(float, ((u32)s) << 16);
    }
    return ((const float*)p)[i];
}

// ---------------- merged front: convert_x + wprep + smalls + bucket_scatter ----------------
// wprep now packs Wcp for the 16x16x32 MFMA B-fragment:
//   chunk t in [0,4096) per layer: l=t&63, c=t>>6, sk=c>>3 (K-step), jt=c&7
//   Wcp[t*8+e] = B[k = sk*32 + (l>>4)*8 + e][j = jt*16 + (l&15)]
//   B[k][j] = (k<128) ? Wl[j][k] : Wr[j][k-128]
#define CH 4096
#define CAPB 3072

__global__ __launch_bounds__(1024) void front_kernel(
    const void* __restrict__ xraw, const int* __restrict__ ei, int E, int N, int cvb,
    u32* __restrict__ xb, int* __restrict__ gcur, u32* __restrict__ csrbkt,
    const void* Wl1, const void* Wr1, const void* Wl2, const void* Wr2,
    const void* Wl3, const void* Wr3, const void* b1, const void* b2,
    const void* b3, const void* Wo, const void* bo,
    u16* __restrict__ Wcp, float* __restrict__ smalls) {
    __shared__ int lhist[1024], loff[1024], lcur[1024], gofs[1024], wsum[16];
    __shared__ u32 ebuf[CH];
    __shared__ u16 ebkt[CH];
    int blk = blockIdx.x;
    int t = threadIdx.x;

    if (blk < cvb) {
        int is64, isbf;
        self_detect(nullptr, (const u32*)xraw, is64, isbf);
        int i = blk * 1024 + t;
        int count4 = N * 16;
        if (i >= count4) return;
        if (isbf) {
            ((u32x4*)xb)[i] = ((const u32x4*)xraw)[i];
        } else {
            typedef float fx4 __attribute__((ext_vector_type(4)));
            const fx4* f4 = (const fx4*)xraw;
            fx4 f0 = f4[2 * i], f1 = f4[2 * i + 1];
            u32x4 o;
            o.x = (u32)f2b(f0.x) | ((u32)f2b(f0.y) << 16);
            o.y = (u32)f2b(f0.z) | ((u32)f2b(f0.w) << 16);
            o.z = (u32)f2b(f1.x) | ((u32)f2b(f1.y) << 16);
            o.w = (u32)f2b(f1.z) | ((u32)f2b(f1.w) << 16);
            ((u32x4*)xb)[i] = o;
        }
        return;
    }
    if (blk < cvb + 12) {
        int is64, isbf;
        self_detect(nullptr, (const u32*)xraw, is64, isbf);
        int tg = (blk - cvb) * 1024 + t;  // 0..12287
        int l = tg >> 12;
        int tt = tg & 4095;
        const void* Wl = (l == 0) ? Wl1 : (l == 1) ? Wl2 : Wl3;
        const void* Wr = (l == 0) ? Wr1 : (l == 1) ? Wr2 : Wr3;
        u16* Wout = Wcp + (size_t)l * 32768;
        int ln = tt & 63;
        int c = tt >> 6;       // 0..63
        int sk = c >> 3;       // K-step 0..7
        int jt = c & 7;        // col-tile 0..7
        int j = jt * 16 + (ln & 15);
        int kb = sk * 32 + (ln >> 4) * 8;
#pragma unroll
        for (int jj = 0; jj < 8; ++jj) {
            int k = kb + jj;
            float v = (k < 128) ? load_f(Wl, isbf, (size_t)j * 128 + k)
                                : load_f(Wr, isbf, (size_t)j * 128 + (k - 128));
            Wout[tt * 8 + jj] = f2b(v);
        }
        return;
    }
    if (blk == cvb + 12) {
        int is64, isbf;
        self_detect(nullptr, (const u32*)xraw, is64, isbf);
        if (t < 642) {
            float v;
            if (t < 128) v = load_f(b1, isbf, t);
            else if (t < 256) v = load_f(b2, isbf, t - 128);
            else if (t < 384) v = load_f(b3, isbf, t - 256);
            else if (t < 640) v = load_f(Wo, isbf, t - 384);
            else v = load_f(bo, isbf, t - 640);
            smalls[t] = v;
        }
        return;
    }

    // ---- scatter role ----
    int is64, isbf;
    self_detect(ei, nullptr, is64, isbf);
    int cbase = (blk - (cvb + 13)) * CH;
    int cn = E - cbase;
    if (cn > CH) cn = CH;
    lhist[t] = 0;
    __syncthreads();
    int mysrc[4], myb[4], mydl[4];
#pragma unroll
    for (int k = 0; k < 4; ++k) {
        int i = t + k * 1024;
        myb[k] = -1;
        if (i < cn) {
            int e = cbase + i;
            int s, d;
            if (is64) {
                s = (int)((const uint2*)ei)[(size_t)e].x;
                d = (int)((const uint2*)ei)[(size_t)E + e].x;
            } else {
                s = ei[(size_t)e];
                d = ei[(size_t)E + e];
            }
            if ((unsigned)s >= (unsigned)N) s = 0;
            if ((unsigned)d >= (unsigned)N) d = 0;
            mysrc[k] = s;
            mydl[k] = d & 255;
            myb[k] = d >> 8;
            atomicAdd(&lhist[myb[k]], 1);
        }
    }
    __syncthreads();
    int lane = t & 63, wid = t >> 6;
    int v = lhist[t];
    int inc = v;
#pragma unroll
    for (int off = 1; off < 64; off <<= 1) {
        int o = __shfl_up(inc, off);
        if (lane >= off) inc += o;
    }
    if (lane == 63) wsum[wid] = inc;
    __syncthreads();
    int wpre = 0;
    for (int w = 0; w < wid; ++w) wpre += wsum[w];
    int excl = wpre + inc - v;
    loff[t] = excl;
    lcur[t] = excl;
    if (v > 0) gofs[t] = atomicAdd(&gcur[t], v);
    __syncthreads();
#pragma unroll
    for (int k = 0; k < 4; ++k) {
        if (myb[k] >= 0) {
            int pos = atomicAdd(&lcur[myb[k]], 1);
            ebuf[pos] = (u32)mysrc[k] | ((u32)mydl[k] << 24);
            ebkt[pos] = (u16)myb[k];
        }
    }
    __syncthreads();
#pragma unroll
    for (int k = 0; k < 4; ++k) {
        int i = t + k * 1024;
        if (i < cn) {
            int bb = ebkt[i];
            int local = gofs[bb] + (i - loff[bb]);
            if (local < CAPB) csrbkt[(size_t)bb * CAPB + local] = ebuf[i];
        }
    }
}

// one block per bucket: counting-sort by dst-low, compact into csr via gtot cursor
__global__ __launch_bounds__(512) void csr_build_kernel(
    const u32* __restrict__ csrbkt, const int* __restrict__ gcur,
    int N, int* __restrict__ gtot,
    int* __restrict__ offs, int* __restrict__ cnt,
    int* __restrict__ csr) {
    __shared__ int lh[256], lcur[256], wsum[4];
    __shared__ int sbase;
    __shared__ u32 sbuf[CAPB];
    int t = threadIdx.x;  // 512
    int b = blockIdx.x;
    int cb = gcur[b];
    if (cb > CAPB) cb = CAPB;
    const u32* bsrc = csrbkt + (size_t)b * CAPB;
    int d0 = b << 8;
    if (t < 256) lh[t] = 0;
    __syncthreads();
    for (int i = t; i < cb; i += 512) atomicAdd(&lh[bsrc[i] >> 24], 1);
    __syncthreads();
    int lane = t & 63, wid = t >> 6;
    if (t < 256) {
        int v = lh[t];
        int inc = v;
#pragma unroll
        for (int off = 1; off < 64; off <<= 1) {
            int o = __shfl_up(inc, off);
            if (lane >= off) inc += o;
        }
        if (lane == 63) wsum[wid] = inc;
    }
    __syncthreads();
    if (t < 256) {
        int v = lh[t];
        int inc = v;
#pragma unroll
        for (int off = 1; off < 64; off <<= 1) {
            int o = __shfl_up(inc, off);
            if (lane >= off) inc += o;
        }
        int wpre = 0;
        for (int w = 0; w < wid; ++w) wpre += wsum[w];
        int excl = wpre + inc - v;
        lcur[t] = excl;
        int d = d0 + t;
        if (d < N) {
            lh[t] = excl;  // stash excl (reuse lh)
            cnt[d] = v;
        }
    }
    if (t == 0) sbase = atomicAdd(gtot, cb);
    __syncthreads();
    int base = sbase;
    if (t < 256) {
        int d = d0 + t;
        if (d < N) offs[d] = base + lh[t];
    }
    for (int i = t; i < cb; i += 512) {
        u32 e = bsrc[i];
        int pos = atomicAdd(&lcur[e >> 24], 1);
        sbuf[pos] = e & 0xFFFFFFu;
    }
    __syncthreads();
    for (int i = t; i < cb; i += 512) csr[base + i] = (int)sbuf[i];
}

// ---------------- aggregation (round-0 proven form, best measured 42.3 µs) ----------------
// At its practical roofline (~2.75 TB/s random-256B HBM). DO NOT TOUCH.

__global__ void agg_kernel(const u32* __restrict__ F2, const int* __restrict__ offs,
                           const int* __restrict__ cnt, const int* __restrict__ csr,
                           u32* __restrict__ Aout, int N, int tstride) {
    int sub = blockIdx.x / tstride;
    int tile = blockIdx.x % tstride;
    int w = threadIdx.x >> 6;
    int lane = threadIdx.x & 63;
    int nd0 = tile * 128 + sub * 16 + w * 4;
    if (nd0 >= N) return;
    int nd1 = nd0 + 4 < N ? nd0 + 4 : N;
    for (int nd = nd0; nd < nd1; ++nd) {
        int start = offs[nd];
        int num = cnt[nd];
        float a0 = 0.f, a1 = 0.f;
        int i = 0;
        for (; i + 8 <= num; i += 8) {
            int s0 = csr[start + i + 0], s1 = csr[start + i + 1];
            int s2 = csr[start + i + 2], s3 = csr[start + i + 3];
            int s4 = csr[start + i + 4], s5 = csr[start + i + 5];
            int s6 = csr[start + i + 6], s7 = csr[start + i + 7];
            u32 u0 = F2[(size_t)s0 * 64 + lane];
            u32 u1 = F2[(size_t)s1 * 64 + lane];
            u32 u2 = F2[(size_t)s2 * 64 + lane];
            u32 u3 = F2[(size_t)s3 * 64 + lane];
            u32 u4 = F2[(size_t)s4 * 64 + lane];
            u32 u5 = F2[(size_t)s5 * 64 + lane];
            u32 u6 = F2[(size_t)s6 * 64 + lane];
            u32 u7 = F2[(size_t)s7 * 64 + lane];
            a0 += lo2f(u0) + lo2f(u1) + lo2f(u2) + lo2f(u3) +
                  lo2f(u4) + lo2f(u5) + lo2f(u6) + lo2f(u7);
            a1 += hi2f(u0) + hi2f(u1) + hi2f(u2) + hi2f(u3) +
                  hi2f(u4) + hi2f(u5) + hi2f(u6) + hi2f(u7);
        }
        for (; i + 4 <= num; i += 4) {
            int s0 = csr[start + i + 0], s1 = csr[start + i + 1];
            int s2 = csr[start + i + 2], s3 = csr[start + i + 3];
            u32 u0 = F2[(size_t)s0 * 64 + lane];
            u32 u1 = F2[(size_t)s1 * 64 + lane];
            u32 u2 = F2[(size_t)s2 * 64 + lane];
            u32 u3 = F2[(size_t)s3 * 64 + lane];
            a0 += lo2f(u0) + lo2f(u1) + lo2f(u2) + lo2f(u3);
            a1 += hi2f(u0) + hi2f(u1) + hi2f(u2) + hi2f(u3);
        }
        for (; i < num; ++i) {
            u32 u = F2[(size_t)csr[start + i] * 64 + lane];
            a0 += lo2f(u);
            a1 += hi2f(u);
        }
        float sc = 1.0f / (float)(num > 1 ? num : 1);
        a0 *= sc;
        a1 *= sc;
        Aout[(size_t)nd * 64 + lane] = (u32)f2b(a0) | ((u32)f2b(a1) << 16);
    }
}

// ---------------- dual-GEMM v3 (16x16x32): F = act(concat(agg,F) @ Wc + b) ----------------
// 16 rows/wave (vs 32 with 32x32x16): 6256 waves = 24.4 waves/CU of work,
// 2x the memory-level parallelism of the grid-limited 32x32 version.
// A-frag: row = lane&15, k = (lane>>4)*8 + e per 32-K step.
// C/D:    col = lane&15, row = (lane>>4)*4 + r  [verified m89/m91].
// Block = 4 waves = 64 nodes; grid = 2*gstride so both halves of agg tile T
// get blockIdx % 8 == T % 8 (XCD affinity preserved).
// Epilogue: per-wave LDS transpose [16][132] u16 (writes 2-way merged,
// reads <=4-way), stores 4x dwordx4/lane. No __syncthreads needed.
__global__ __launch_bounds__(256, 4) void gemm_kernel(
    const u32* __restrict__ aggb, u32* Fio,
    const u16* __restrict__ Wcp, const float* __restrict__ biasf,
    int N, int relu, const float* __restrict__ headw,
    const u32* __restrict__ xw, void* __restrict__ outp, int gstride) {
    __shared__ u16 ldsT[4][16][132];
    int tid = threadIdx.x;
    int w = tid >> 6;
    int lane = tid & 63;
    int r16 = lane & 15;
    int g4 = lane >> 4;
    int tile = blockIdx.x % gstride;
    int half = blockIdx.x / gstride;
    int nbase = tile * 128 + half * 64;
    if (nbase >= N) return;
    int nd0 = nbase + w * 16;
    int node = nd0 + r16;
    int nodeC = (node < N) ? node : (N - 1);
    const u32* aRow = aggb + (size_t)nodeC * 64 + g4 * 4;  // + k-group offset (8 bf16)
    const u32* fRow = Fio + (size_t)nodeC * 64 + g4 * 4;

    floatx4 acc[8];
#pragma unroll
    for (int jt = 0; jt < 8; ++jt) acc[jt] = 0.0f;

#pragma unroll
    for (int s = 0; s < 8; ++s) {
        const u32* ap = (s < 4) ? (aRow + (size_t)s * 16) : (fRow + (size_t)(s - 4) * 16);
        bf16x8 a = *reinterpret_cast<const bf16x8*>(ap);
        const u16* bp = Wcp + (size_t)((s * 8) * 64 + lane) * 8;
#pragma unroll
        for (int jt = 0; jt < 8; ++jt) {
            bf16x8 b = *reinterpret_cast<const bf16x8*>(bp + (size_t)jt * 64 * 8);
            acc[jt] = __builtin_amdgcn_mfma_f32_16x16x32_bf16(a, b, acc[jt], 0, 0, 0);
        }
    }

    if (outp == nullptr) {
        // write: lane (r16,g4), reg r -> LDS[row = g4*4+r][col = jt*16+r16]
#pragma unroll
        for (int jt = 0; jt < 8; ++jt) {
            int j = jt * 16 + r16;
            float bf = biasf[j];
#pragma unroll
            for (int r = 0; r < 4; ++r) {
                float v = acc[jt][r] + bf;
                if (relu) v = fmaxf(v, 0.0f);
                ldsT[w][g4 * 4 + r][j] = f2b(v);
            }
        }
        // read back: lane owns row r16, segment g4 (32 u16 = 64 B), 4x 16 B
        int rowg = nd0 + r16;
        if (rowg < N) {
            u32* drow = &Fio[(size_t)rowg * 64 + g4 * 16];
#pragma unroll
            for (int i = 0; i < 4; ++i) {
                const u16* lp = &ldsT[w][r16][g4 * 32 + i * 8];
                uint2 lo = *reinterpret_cast<const uint2*>(lp);
                uint2 hi = *reinterpret_cast<const uint2*>(lp + 4);
                u32x4 o;
                o.x = lo.x; o.y = lo.y; o.z = hi.x; o.w = hi.y;
                *reinterpret_cast<u32x4*>(drow + i * 4) = o;
            }
        }
    } else {
        // fused head: h = acc + bl3; out = (h.Wo0 + bo0, h.Wo1 + bo1)
        int is64, isbf;
        self_detect(nullptr, xw, is64, isbf);  // full wave active
#pragma unroll
        for (int r = 0; r < 4; ++r) {
            float p0 = 0.f, p1 = 0.f;
#pragma unroll
            for (int jt = 0; jt < 8; ++jt) {
                int j = jt * 16 + r16;
                float v = acc[jt][r] + biasf[j];
                p0 += v * headw[j];
                p1 += v * headw[128 + j];
            }
            // reduce over the 16 cols (lanes with same g4)
#pragma unroll
            for (int off = 8; off > 0; off >>= 1) {
                p0 += __shfl_xor(p0, off);
                p1 += __shfl_xor(p1, off);
            }
            if (r16 == 0) {
                int nodeS = nd0 + g4 * 4 + r;
                if (nodeS < N) {
                    float o0 = p0 + headw[256];  // bo0
                    float o1 = p1 + headw[257];  // bo1
                    if (isbf)
                        ((u32*)outp)[nodeS] = (u32)f2b(o0) | ((u32)f2b(o1) << 16);
                    else
                        ((float2*)outp)[nodeS] = make_float2(o0, o1);
                }
            }
        }
    }
}

extern "C" void kernel_launch(void* const* d_in, const int* in_sizes, int n_in,
                              void* d_out, int out_size, void* d_ws, size_t ws_size,
                              hipStream_t stream) {
    const int N = in_sizes[0] / 128;
    const int E = in_sizes[1] / 2;

    const void* x = d_in[0];
    const int* ei = (const int*)d_in[1];
    const void* Wl[3] = {d_in[2], d_in[5], d_in[8]};
    const void* bl[3] = {d_in[3], d_in[6], d_in[9]};
    const void* Wr[3] = {d_in[4], d_in[7], d_in[10]};
    const void* Wo = d_in[11];
    const void* bo = d_in[12];

    // workspace bump allocator (256B aligned)
    char* p = (char*)d_ws;
    auto alloc = [&](size_t bytes) -> char* {
        char* r = p;
        p += (bytes + 255) & ~(size_t)255;
        return r;
    };
    int* offs = (int*)alloc((size_t)N * 4);
    int* cnt = (int*)alloc((size_t)N * 4);
    float* smalls = (float*)alloc(642 * 4);
    int* gcur = (int*)alloc(1025 * 4);  // [1024] = gtot
    int* csr = (int*)alloc(((size_t)E + CAPB + 64) * 4);  // over-alloc: padded reads safe
    u16* Wcp = (u16*)alloc((size_t)3 * 4096 * 8 * 2);
    u32* xb = (u32*)alloc((size_t)(N + 1) * 64 * 4);
    u32* aggb = (u32*)alloc((size_t)N * 64 * 4);  // agg features; aliased as csrbkt during build
    u32* csrbkt = aggb;                            // dead until layers start
    int* gtot = gcur + 1024;
    (void)ws_size;

    const int NB = (N + 255) / 256;          // buckets
    const int cvb = (N * 16 + 1023) / 1024;  // convert blocks (1024 thr)
    const int sb = (E + CH - 1) / CH;        // scatter blocks
    const int gb = (N + 127) / 128;          // agg tiles (128 nodes)
    const int tstride = (gb + 7) & ~7;       // tile stride, mult of 8 (XCD affinity)
    const int ab = 8 * tstride;              // agg blocks: 8 sub-blocks x tstride tiles
    const int gstride = tstride;             // gemm: 2 half-blocks per tile
    const int ggrid = 2 * gstride;

    hipMemsetAsync(gcur, 0, 1025 * 4, stream);
    front_kernel<<<cvb + 13 + sb, 1024, 0, stream>>>(
        x, ei, E, N, cvb, xb, gcur, csrbkt,
        Wl[0], Wr[0], Wl[1], Wr[1], Wl[2], Wr[2],
        bl[0], bl[1], bl[2], Wo, bo, Wcp, smalls);
    csr_build_kernel<<<NB, 512, 0, stream>>>(csrbkt, gcur, N, gtot, offs, cnt, csr);

    // layer 1
    agg_kernel<<<ab, 256, 0, stream>>>(xb, offs, cnt, csr, aggb, N, tstride);
    gemm_kernel<<<ggrid, 256, 0, stream>>>(aggb, xb, Wcp, smalls, N, 1, nullptr, nullptr, nullptr, gstride);
    // layer 2
    agg_kernel<<<ab, 256, 0, stream>>>(xb, offs, cnt, csr, aggb, N, tstride);
    gemm_kernel<<<ggrid, 256, 0, stream>>>(aggb, xb, Wcp + 32768, smalls + 128, N, 1, nullptr, nullptr, nullptr, gstride);
    // layer 3 + fused head
    agg_kernel<<<ab, 256, 0, stream>>>(xb, offs, cnt, csr, aggb, N, tstride);
    gemm_kernel<<<ggrid, 256, 0, stream>>>(aggb, xb, Wcp + 65536, smalls + 256, N, 0,
                                           smalls + 384, (const u32*)x, d_out, gstride);
}

// Round 8
// 327.268 us; speedup vs baseline: 1.0464x; 1.0464x over previous
//
#include <hip/hip_runtime.h>
#include <stdint.h>

typedef unsigned int u32;
typedef unsigned short u16;
typedef __bf16 bf16x8 __attribute__((ext_vector_type(8)));
typedef float floatx16 __attribute__((ext_vector_type(16)));
typedef u32 u32x4 __attribute__((ext_vector_type(4)));
typedef float floatx4 __attribute__((ext_vector_type(4)));

__device__ __forceinline__ u16 f2b(float f) {
    u32 u = __builtin_bit_cast(u32, f);
    u32 r = u + 0x7FFFu + ((u >> 16) & 1u);
    return (u16)(r >> 16);
}
__device__ __forceinline__ float lo2f(u32 u) { return __builtin_bit_cast(float, u << 16); }
__device__ __forceinline__ float hi2f(u32 u) { return __builtin_bit_cast(float, u & 0xFFFF0000u); }

// ---------------- wave-uniform self-detection ----------------
__device__ __forceinline__ void self_detect(const int* ei, const u32* xw, int& is64, int& isbf) {
    int lane = threadIdx.x & 63;
    int v = ei ? ei[2 * lane + 1] : 0;
    unsigned long long b1 = __ballot(v == 0);
    u32 w = xw ? xw[lane] : 0;
    u32 e = (w >> 7) & 0xFF;
    int plaus = (e == 0) || (e >= 90 && e <= 140);
    unsigned long long b2 = __ballot(plaus);
    is64 = (b1 == ~0ULL) ? 1 : 0;
    isbf = (b2 == ~0ULL) ? 1 : 0;
}

__device__ __forceinline__ float load_f(const void* __restrict__ p, int isbf, size_t i) {
    if (isbf) {
        u16 s = ((const u16*)p)[i];
        return __builtin_bit_cast(float, ((u32)s) << 16);
    }
    return ((const float*)p)[i];
}

// ---------------- merged front: convert_x + wprep + smalls + bucket_scatter ----------------
// (proven R6 form: 32x32 Wcp packing, uint2 scatter loads — DO NOT TOUCH)
#define CH 4096
#define CAPB 3072

__global__ __launch_bounds__(1024) void front_kernel(
    const void* __restrict__ xraw, const int* __restrict__ ei, int E, int N, int cvb,
    u32* __restrict__ xb, int* __restrict__ gcur, u32* __restrict__ csrbkt,
    const void* Wl1, const void* Wr1, const void* Wl2, const void* Wr2,
    const void* Wl3, const void* Wr3, const void* b1, const void* b2,
    const void* b3, const void* Wo, const void* bo,
    u16* __restrict__ Wcp, float* __restrict__ smalls) {
    __shared__ int lhist[1024], loff[1024], lcur[1024], gofs[1024], wsum[16];
    __shared__ u32 ebuf[CH];
    __shared__ u16 ebkt[CH];
    int blk = blockIdx.x;
    int t = threadIdx.x;

    if (blk < cvb) {
        int is64, isbf;
        self_detect(nullptr, (const u32*)xraw, is64, isbf);
        int i = blk * 1024 + t;
        int count4 = N * 16;
        if (i >= count4) return;
        if (isbf) {
            ((u32x4*)xb)[i] = ((const u32x4*)xraw)[i];
        } else {
            typedef float fx4 __attribute__((ext_vector_type(4)));
            const fx4* f4 = (const fx4*)xraw;
            fx4 f0 = f4[2 * i], f1 = f4[2 * i + 1];
            u32x4 o;
            o.x = (u32)f2b(f0.x) | ((u32)f2b(f0.y) << 16);
            o.y = (u32)f2b(f0.z) | ((u32)f2b(f0.w) << 16);
            o.z = (u32)f2b(f1.x) | ((u32)f2b(f1.y) << 16);
            o.w = (u32)f2b(f1.z) | ((u32)f2b(f1.w) << 16);
            ((u32x4*)xb)[i] = o;
        }
        return;
    }
    if (blk < cvb + 12) {
        int is64, isbf;
        self_detect(nullptr, (const u32*)xraw, is64, isbf);
        int tg = (blk - cvb) * 1024 + t;  // 0..12287
        int l = tg >> 12;
        int tt = tg & 4095;
        const void* Wl = (l == 0) ? Wl1 : (l == 1) ? Wl2 : Wl3;
        const void* Wr = (l == 0) ? Wr1 : (l == 1) ? Wr2 : Wr3;
        u16* Wout = Wcp + (size_t)l * 32768;
        int lane = tt & 63;
        int jt = (tt >> 6) & 3;
        int s = tt >> 8;
        int n = lane & 31;
        int q = lane >> 5;
        int j = jt * 32 + n;
#pragma unroll
        for (int jj = 0; jj < 8; ++jj) {
            int k = s * 16 + q * 8 + jj;
            float v = (k < 128) ? load_f(Wl, isbf, (size_t)j * 128 + k)
                                : load_f(Wr, isbf, (size_t)j * 128 + (k - 128));
            Wout[tt * 8 + jj] = f2b(v);
        }
        return;
    }
    if (blk == cvb + 12) {
        int is64, isbf;
        self_detect(nullptr, (const u32*)xraw, is64, isbf);
        if (t < 642) {
            float v;
            if (t < 128) v = load_f(b1, isbf, t);
            else if (t < 256) v = load_f(b2, isbf, t - 128);
            else if (t < 384) v = load_f(b3, isbf, t - 256);
            else if (t < 640) v = load_f(Wo, isbf, t - 384);
            else v = load_f(bo, isbf, t - 640);
            smalls[t] = v;
        }
        return;
    }

    // ---- scatter role ----
    int is64, isbf;
    self_detect(ei, nullptr, is64, isbf);
    int cbase = (blk - (cvb + 13)) * CH;
    int cn = E - cbase;
    if (cn > CH) cn = CH;
    lhist[t] = 0;
    __syncthreads();
    int mysrc[4], myb[4], mydl[4];
#pragma unroll
    for (int k = 0; k < 4; ++k) {
        int i = t + k * 1024;
        myb[k] = -1;
        if (i < cn) {
            int e = cbase + i;
            int s, d;
            if (is64) {
                s = (int)((const uint2*)ei)[(size_t)e].x;
                d = (int)((const uint2*)ei)[(size_t)E + e].x;
            } else {
                s = ei[(size_t)e];
                d = ei[(size_t)E + e];
            }
            if ((unsigned)s >= (unsigned)N) s = 0;
            if ((unsigned)d >= (unsigned)N) d = 0;
            mysrc[k] = s;
            mydl[k] = d & 255;
            myb[k] = d >> 8;
            atomicAdd(&lhist[myb[k]], 1);
        }
    }
    __syncthreads();
    int lane = t & 63, wid = t >> 6;
    int v = lhist[t];
    int inc = v;
#pragma unroll
    for (int off = 1; off < 64; off <<= 1) {
        int o = __shfl_up(inc, off);
        if (lane >= off) inc += o;
    }
    if (lane == 63) wsum[wid] = inc;
    __syncthreads();
    int wpre = 0;
    for (int w = 0; w < wid; ++w) wpre += wsum[w];
    int excl = wpre + inc - v;
    loff[t] = excl;
    lcur[t] = excl;
    if (v > 0) gofs[t] = atomicAdd(&gcur[t], v);
    __syncthreads();
#pragma unroll
    for (int k = 0; k < 4; ++k) {
        if (myb[k] >= 0) {
            int pos = atomicAdd(&lcur[myb[k]], 1);
            ebuf[pos] = (u32)mysrc[k] | ((u32)mydl[k] << 24);
            ebkt[pos] = (u16)myb[k];
        }
    }
    __syncthreads();
    // write runs: consecutive i within a bucket -> consecutive global slots
#pragma unroll
    for (int k = 0; k < 4; ++k) {
        int i = t + k * 1024;
        if (i < cn) {
            int bb = ebkt[i];
            int local = gofs[bb] + (i - loff[bb]);
            if (local < CAPB) csrbkt[(size_t)bb * CAPB + local] = ebuf[i];
        }
    }
}

// one block per bucket: counting-sort by dst-low, compact into csr via gtot cursor
// (proven round-5/6 form, 512 threads)
__global__ __launch_bounds__(512) void csr_build_kernel(
    const u32* __restrict__ csrbkt, const int* __restrict__ gcur,
    int N, int* __restrict__ gtot,
    int* __restrict__ offs, int* __restrict__ cnt,
    int* __restrict__ csr) {
    __shared__ int lh[256], lcur[256], wsum[4];
    __shared__ int sbase;
    __shared__ u32 sbuf[CAPB];
    int t = threadIdx.x;  // 512
    int b = blockIdx.x;
    int cb = gcur[b];
    if (cb > CAPB) cb = CAPB;
    const u32* bsrc = csrbkt + (size_t)b * CAPB;
    int d0 = b << 8;
    if (t < 256) lh[t] = 0;
    __syncthreads();
    for (int i = t; i < cb; i += 512) atomicAdd(&lh[bsrc[i] >> 24], 1);
    __syncthreads();
    int lane = t & 63, wid = t >> 6;
    if (t < 256) {
        int v = lh[t];
        int inc = v;
#pragma unroll
        for (int off = 1; off < 64; off <<= 1) {
            int o = __shfl_up(inc, off);
            if (lane >= off) inc += o;
        }
        if (lane == 63) wsum[wid] = inc;
    }
    __syncthreads();
    if (t < 256) {
        int v = lh[t];
        int inc = v;
#pragma unroll
        for (int off = 1; off < 64; off <<= 1) {
            int o = __shfl_up(inc, off);
            if (lane >= off) inc += o;
        }
        int wpre = 0;
        for (int w = 0; w < wid; ++w) wpre += wsum[w];
        int excl = wpre + inc - v;
        lcur[t] = excl;
        int d = d0 + t;
        if (d < N) {
            lh[t] = excl;  // stash excl (reuse lh)
            cnt[d] = v;
        }
    }
    if (t == 0) sbase = atomicAdd(gtot, cb);
    __syncthreads();
    int base = sbase;
    if (t < 256) {
        int d = d0 + t;
        if (d < N) offs[d] = base + lh[t];
    }
    for (int i = t; i < cb; i += 512) {
        u32 e = bsrc[i];
        int pos = atomicAdd(&lcur[e >> 24], 1);
        sbuf[pos] = e & 0xFFFFFFu;
    }
    __syncthreads();
    for (int i = t; i < cb; i += 512) csr[base + i] = (int)sbuf[i];
}

// ---------------- aggregation (round-0 proven form, best measured 42.3 µs) ----------------
// At its practical roofline (~2.75 TB/s random-256B HBM). DO NOT TOUCH.

__global__ void agg_kernel(const u32* __restrict__ F2, const int* __restrict__ offs,
                           const int* __restrict__ cnt, const int* __restrict__ csr,
                           u32* __restrict__ Aout, int N, int tstride) {
    int sub = blockIdx.x / tstride;
    int tile = blockIdx.x % tstride;
    int w = threadIdx.x >> 6;
    int lane = threadIdx.x & 63;
    int nd0 = tile * 128 + sub * 16 + w * 4;
    if (nd0 >= N) return;
    int nd1 = nd0 + 4 < N ? nd0 + 4 : N;
    for (int nd = nd0; nd < nd1; ++nd) {
        int start = offs[nd];
        int num = cnt[nd];
        float a0 = 0.f, a1 = 0.f;
        int i = 0;
        for (; i + 8 <= num; i += 8) {
            int s0 = csr[start + i + 0], s1 = csr[start + i + 1];
            int s2 = csr[start + i + 2], s3 = csr[start + i + 3];
            int s4 = csr[start + i + 4], s5 = csr[start + i + 5];
            int s6 = csr[start + i + 6], s7 = csr[start + i + 7];
            u32 u0 = F2[(size_t)s0 * 64 + lane];
            u32 u1 = F2[(size_t)s1 * 64 + lane];
            u32 u2 = F2[(size_t)s2 * 64 + lane];
            u32 u3 = F2[(size_t)s3 * 64 + lane];
            u32 u4 = F2[(size_t)s4 * 64 + lane];
            u32 u5 = F2[(size_t)s5 * 64 + lane];
            u32 u6 = F2[(size_t)s6 * 64 + lane];
            u32 u7 = F2[(size_t)s7 * 64 + lane];
            a0 += lo2f(u0) + lo2f(u1) + lo2f(u2) + lo2f(u3) +
                  lo2f(u4) + lo2f(u5) + lo2f(u6) + lo2f(u7);
            a1 += hi2f(u0) + hi2f(u1) + hi2f(u2) + hi2f(u3) +
                  hi2f(u4) + hi2f(u5) + hi2f(u6) + hi2f(u7);
        }
        for (; i + 4 <= num; i += 4) {
            int s0 = csr[start + i + 0], s1 = csr[start + i + 1];
            int s2 = csr[start + i + 2], s3 = csr[start + i + 3];
            u32 u0 = F2[(size_t)s0 * 64 + lane];
            u32 u1 = F2[(size_t)s1 * 64 + lane];
            u32 u2 = F2[(size_t)s2 * 64 + lane];
            u32 u3 = F2[(size_t)s3 * 64 + lane];
            a0 += lo2f(u0) + lo2f(u1) + lo2f(u2) + lo2f(u3);
            a1 += hi2f(u0) + hi2f(u1) + hi2f(u2) + hi2f(u3);
        }
        for (; i < num; ++i) {
            u32 u = F2[(size_t)csr[start + i] * 64 + lane];
            a0 += lo2f(u);
            a1 += hi2f(u);
        }
        float sc = 1.0f / (float)(num > 1 ? num : 1);
        a0 *= sc;
        a1 *= sc;
        Aout[(size_t)nd * 64 + lane] = (u32)f2b(a0) | ((u32)f2b(a1) << 16);
    }
}

// ---------------- dual-GEMM v4: A-hoist + B-double-buffer ----------------
// Same math/layout as proven R6 (32x32x16, LDS-transpose epilogue). Loop
// restructured for ILP: all 16 A-fragments (aggb+Fio rows, HBM) loaded into
// registers BEFORE any MFMA -> one exposed HBM latency per wave instead of
// up to 16 (the acc chain serialized per-step loads). B-fragments (Wcp,
// L2-hot) prefetched one step ahead of the 4-MFMA group.
// __launch_bounds__(256, 2): VGPR ~176 (64 a_frags + 64 acc + 32 B + addr)
// -> 8 waves/CU tier; intentional, the lever is in-wave ILP not TLP.
__global__ __launch_bounds__(256, 2) void gemm_kernel(
    const u32* __restrict__ aggb, u32* Fio,
    const u16* __restrict__ Wcp, const float* __restrict__ biasf,
    int N, int relu, const float* __restrict__ headw,
    const u32* __restrict__ xw, void* __restrict__ outp) {
    __shared__ u16 ldsT[4][32][68];
    int tid = threadIdx.x;
    int w = tid >> 6;
    int lane = tid & 63;
    int nbase = blockIdx.x * 128;
    int n = lane & 31;
    int q = lane >> 5;
    int rowl = w * 32 + n;
    int node = nbase + rowl;
    int nodeC = (node < N) ? node : (N - 1);
    const u32* aRow = aggb + (size_t)nodeC * 64 + q * 4;
    const u32* fRow = Fio + (size_t)nodeC * 64 + q * 4;

    // hoist all 16 A-fragments (independent HBM loads, issued back-to-back)
    bf16x8 a_frags[16];
#pragma unroll
    for (int s = 0; s < 8; ++s)
        a_frags[s] = *reinterpret_cast<const bf16x8*>(aRow + (size_t)s * 8);
#pragma unroll
    for (int s = 0; s < 8; ++s)
        a_frags[8 + s] = *reinterpret_cast<const bf16x8*>(fRow + (size_t)s * 8);

    floatx16 acc0 = 0.0f, acc1 = 0.0f, acc2 = 0.0f, acc3 = 0.0f;

    // B: step stride 4*64*8 = 2048 u16, jt stride 64*8 = 512 u16
    const u16* bpb = Wcp + (size_t)lane * 8;
    bf16x8 c0 = *reinterpret_cast<const bf16x8*>(bpb);
    bf16x8 c1 = *reinterpret_cast<const bf16x8*>(bpb + 512);
    bf16x8 c2 = *reinterpret_cast<const bf16x8*>(bpb + 1024);
    bf16x8 c3 = *reinterpret_cast<const bf16x8*>(bpb + 1536);
#pragma unroll
    for (int s = 0; s < 16; ++s) {
        bf16x8 n0, n1, n2, n3;
        if (s < 15) {
            const u16* np = bpb + (size_t)(s + 1) * 2048;
            n0 = *reinterpret_cast<const bf16x8*>(np);
            n1 = *reinterpret_cast<const bf16x8*>(np + 512);
            n2 = *reinterpret_cast<const bf16x8*>(np + 1024);
            n3 = *reinterpret_cast<const bf16x8*>(np + 1536);
        }
        acc0 = __builtin_amdgcn_mfma_f32_32x32x16_bf16(a_frags[s], c0, acc0, 0, 0, 0);
        acc1 = __builtin_amdgcn_mfma_f32_32x32x16_bf16(a_frags[s], c1, acc1, 0, 0, 0);
        acc2 = __builtin_amdgcn_mfma_f32_32x32x16_bf16(a_frags[s], c2, acc2, 0, 0, 0);
        acc3 = __builtin_amdgcn_mfma_f32_32x32x16_bf16(a_frags[s], c3, acc3, 0, 0, 0);
        if (s < 15) { c0 = n0; c1 = n1; c2 = n2; c3 = n3; }
    }

    int mbase = nbase + w * 32;
    floatx16 accs[4] = {acc0, acc1, acc2, acc3};
    // C/D: col=lane&31, row=(r&3)+8*(r>>2)+4*(lane>>5)  [verified m74/m101]

    if (outp == nullptr) {
        int rowg = mbase + n;  // the row this lane stores after transpose
        int okrow = rowg < N;
#pragma unroll
        for (int h = 0; h < 2; ++h) {
            // write phase: two col-quadrants (64 cols) of this wave's 32 rows
#pragma unroll
            for (int jt2 = 0; jt2 < 2; ++jt2) {
                int jt = h * 2 + jt2;
                int j0 = jt * 32 + n;
                float bf = biasf[j0];
#pragma unroll
                for (int r = 0; r < 16; ++r) {
                    int row = (r & 3) + 8 * (r >> 2) + 4 * q;
                    float v = accs[jt][r] + bf;
                    if (relu) v = fmaxf(v, 0.0f);
                    ldsT[w][row][jt2 * 32 + n] = f2b(v);
                }
            }
            // read back + coalesced store: lane (n,q) owns row n, 16 B x4
#pragma unroll
            for (int i = 0; i < 4; ++i) {
                const u16* lp = &ldsT[w][n][q * 8 + i * 16];
                uint2 lo = *reinterpret_cast<const uint2*>(lp);
                uint2 hi = *reinterpret_cast<const uint2*>(lp + 4);
                if (okrow) {
                    u32x4 o;
                    o.x = lo.x; o.y = lo.y; o.z = hi.x; o.w = hi.y;
                    *reinterpret_cast<u32x4*>(&Fio[(size_t)rowg * 64 + h * 32 + q * 4 + i * 8]) = o;
                }
            }
        }
    } else {
        // fused head: out[node] = (h·Wo0 + bo0, h·Wo1 + bo1); h = acc + bl3
        int is64, isbf;
        self_detect(nullptr, xw, is64, isbf);  // full wave active here
#pragma unroll
        for (int r = 0; r < 16; ++r) {
            float p0 = 0.f, p1 = 0.f;
#pragma unroll
            for (int jt = 0; jt < 4; ++jt) {
                int j = jt * 32 + n;
                float v = accs[jt][r] + biasf[j];
                p0 += v * headw[j];
                p1 += v * headw[128 + j];
            }
#pragma unroll
            for (int off = 16; off > 0; off >>= 1) {
                p0 += __shfl_xor(p0, off);
                p1 += __shfl_xor(p1, off);
            }
            if (n == 0) {
                int row = (r & 3) + 8 * (r >> 2) + 4 * q;
                int nodeS = mbase + row;
                if (nodeS < N) {
                    float o0 = p0 + headw[256];  // bo0
                    float o1 = p1 + headw[257];  // bo1
                    if (isbf)
                        ((u32*)outp)[nodeS] = (u32)f2b(o0) | ((u32)f2b(o1) << 16);
                    else
                        ((float2*)outp)[nodeS] = make_float2(o0, o1);
                }
            }
        }
    }
}

extern "C" void kernel_launch(void* const* d_in, const int* in_sizes, int n_in,
                              void* d_out, int out_size, void* d_ws, size_t ws_size,
                              hipStream_t stream) {
    const int N = in_sizes[0] / 128;
    const int E = in_sizes[1] / 2;

    const void* x = d_in[0];
    const int* ei = (const int*)d_in[1];
    const void* Wl[3] = {d_in[2], d_in[5], d_in[8]};
    const void* bl[3] = {d_in[3], d_in[6], d_in[9]};
    const void* Wr[3] = {d_in[4], d_in[7], d_in[10]};
    const void* Wo = d_in[11];
    const void* bo = d_in[12];

    // workspace bump allocator (256B aligned)
    char* p = (char*)d_ws;
    auto alloc = [&](size_t bytes) -> char* {
        char* r = p;
        p += (bytes + 255) & ~(size_t)255;
        return r;
    };
    int* offs = (int*)alloc((size_t)N * 4);
    int* cnt = (int*)alloc((size_t)N * 4);
    float* smalls = (float*)alloc(642 * 4);
    int* gcur = (int*)alloc(1025 * 4);  // [1024] = gtot
    int* csr = (int*)alloc(((size_t)E + CAPB + 64) * 4);  // over-alloc: padded reads safe
    u16* Wcp = (u16*)alloc((size_t)3 * 4096 * 8 * 2);
    u32* xb = (u32*)alloc((size_t)(N + 1) * 64 * 4);
    u32* aggb = (u32*)alloc((size_t)N * 64 * 4);  // agg features; aliased as csrbkt during build
    u32* csrbkt = aggb;                            // dead until layers start
    int* gtot = gcur + 1024;
    (void)ws_size;

    const int NB = (N + 255) / 256;          // buckets
    const int cvb = (N * 16 + 1023) / 1024;  // convert blocks (1024 thr)
    const int sb = (E + CH - 1) / CH;        // scatter blocks
    const int gb = (N + 127) / 128;          // gemm blocks (tiles)
    const int tstride = (gb + 7) & ~7;       // tile stride, mult of 8 (XCD affinity)
    const int ab = 8 * tstride;              // agg blocks: 8 sub-blocks x tstride tiles

    hipMemsetAsync(gcur, 0, 1025 * 4, stream);
    front_kernel<<<cvb + 13 + sb, 1024, 0, stream>>>(
        x, ei, E, N, cvb, xb, gcur, csrbkt,
        Wl[0], Wr[0], Wl[1], Wr[1], Wl[2], Wr[2],
        bl[0], bl[1], bl[2], Wo, bo, Wcp, smalls);
    csr_build_kernel<<<NB, 512, 0, stream>>>(csrbkt, gcur, N, gtot, offs, cnt, csr);

    // layer 1
    agg_kernel<<<ab, 256, 0, stream>>>(xb, offs, cnt, csr, aggb, N, tstride);
    gemm_kernel<<<gb, 256, 0, stream>>>(aggb, xb, Wcp, smalls, N, 1, nullptr, nullptr, nullptr);
    // layer 2
    agg_kernel<<<ab, 256, 0, stream>>>(xb, offs, cnt, csr, aggb, N, tstride);
    gemm_kernel<<<gb, 256, 0, stream>>>(aggb, xb, Wcp + 32768, smalls + 128, N, 1, nullptr, nullptr, nullptr);
    // layer 3 + fused head
    agg_kernel<<<ab, 256, 0, stream>>>(xb, offs, cnt, csr, aggb, N, tstride);
    gemm_kernel<<<gb, 256, 0, stream>>>(aggb, xb, Wcp + 65536, smalls + 256, N, 0,
                                        smalls + 384, (const u32*)x, d_out);
}

// Round 9
// 325.754 us; speedup vs baseline: 1.0513x; 1.0046x over previous
//
#include <hip/hip_runtime.h>
#include <stdint.h>

typedef unsigned int u32;
typedef unsigned short u16;
typedef __bf16 bf16x8 __attribute__((ext_vector_type(8)));
typedef float floatx4 __attribute__((ext_vector_type(4)));
typedef u32 u32x4 __attribute__((ext_vector_type(4)));

__device__ __forceinline__ u16 f2b(float f) {
    u32 u = __builtin_bit_cast(u32, f);
    u32 r = u + 0x7FFFu + ((u >> 16) & 1u);
    return (u16)(r >> 16);
}
__device__ __forceinline__ float lo2f(u32 u) { return __builtin_bit_cast(float, u << 16); }
__device__ __forceinline__ float hi2f(u32 u) { return __builtin_bit_cast(float, u & 0xFFFF0000u); }

// ---------------- wave-uniform self-detection ----------------
__device__ __forceinline__ void self_detect(const int* ei, const u32* xw, int& is64, int& isbf) {
    int lane = threadIdx.x & 63;
    int v = ei ? ei[2 * lane + 1] : 0;
    unsigned long long b1 = __ballot(v == 0);
    u32 w = xw ? xw[lane] : 0;
    u32 e = (w >> 7) & 0xFF;
    int plaus = (e == 0) || (e >= 90 && e <= 140);
    unsigned long long b2 = __ballot(plaus);
    is64 = (b1 == ~0ULL) ? 1 : 0;
    isbf = (b2 == ~0ULL) ? 1 : 0;
}

__device__ __forceinline__ float load_f(const void* __restrict__ p, int isbf, size_t i) {
    if (isbf) {
        u16 s = ((const u16*)p)[i];
        return __builtin_bit_cast(float, ((u32)s) << 16);
    }
    return ((const float*)p)[i];
}

// ---------------- merged front: convert_x + wprep + smalls + bucket_scatter ----------------
// wprep packs Wcp for 16x16x32 MFMA B-frag (verified correct in R7 run):
//   chunk t in [0,4096): l=t&63, c=t>>6, sk=c>>3 (K-step), jt=c&7
//   Wcp[t*8+e] = B[k = sk*32 + (l>>4)*8 + e][j = jt*16 + (l&15)]
//   B[k][j] = (k<128) ? Wl[j][k] : Wr[j][k-128]
#define CH 4096
#define CAPB 3072

__global__ __launch_bounds__(1024) void front_kernel(
    const void* __restrict__ xraw, const int* __restrict__ ei, int E, int N, int cvb,
    u32* __restrict__ xb, int* __restrict__ gcur, u32* __restrict__ csrbkt,
    const void* Wl1, const void* Wr1, const void* Wl2, const void* Wr2,
    const void* Wl3, const void* Wr3, const void* b1, const void* b2,
    const void* b3, const void* Wo, const void* bo,
    u16* __restrict__ Wcp, float* __restrict__ smalls) {
    __shared__ int lhist[1024], loff[1024], lcur[1024], gofs[1024], wsum[16];
    __shared__ u32 ebuf[CH];
    __shared__ u16 ebkt[CH];
    int blk = blockIdx.x;
    int t = threadIdx.x;

    if (blk < cvb) {
        int is64, isbf;
        self_detect(nullptr, (const u32*)xraw, is64, isbf);
        int i = blk * 1024 + t;
        int count4 = N * 16;
        if (i >= count4) return;
        if (isbf) {
            ((u32x4*)xb)[i] = ((const u32x4*)xraw)[i];
        } else {
            typedef float fx4 __attribute__((ext_vector_type(4)));
            const fx4* f4 = (const fx4*)xraw;
            fx4 f0 = f4[2 * i], f1 = f4[2 * i + 1];
            u32x4 o;
            o.x = (u32)f2b(f0.x) | ((u32)f2b(f0.y) << 16);
            o.y = (u32)f2b(f0.z) | ((u32)f2b(f0.w) << 16);
            o.z = (u32)f2b(f1.x) | ((u32)f2b(f1.y) << 16);
            o.w = (u32)f2b(f1.z) | ((u32)f2b(f1.w) << 16);
            ((u32x4*)xb)[i] = o;
        }
        return;
    }
    if (blk < cvb + 12) {
        int is64, isbf;
        self_detect(nullptr, (const u32*)xraw, is64, isbf);
        int tg = (blk - cvb) * 1024 + t;  // 0..12287
        int l = tg >> 12;
        int tt = tg & 4095;
        const void* Wl = (l == 0) ? Wl1 : (l == 1) ? Wl2 : Wl3;
        const void* Wr = (l == 0) ? Wr1 : (l == 1) ? Wr2 : Wr3;
        u16* Wout = Wcp + (size_t)l * 32768;
        int ln = tt & 63;
        int c = tt >> 6;   // 0..63
        int sk = c >> 3;   // K-step 0..7
        int jt = c & 7;    // col-tile 0..7
        int j = jt * 16 + (ln & 15);
        int kb = sk * 32 + (ln >> 4) * 8;
#pragma unroll
        for (int jj = 0; jj < 8; ++jj) {
            int k = kb + jj;
            float v = (k < 128) ? load_f(Wl, isbf, (size_t)j * 128 + k)
                                : load_f(Wr, isbf, (size_t)j * 128 + (k - 128));
            Wout[tt * 8 + jj] = f2b(v);
        }
        return;
    }
    if (blk == cvb + 12) {
        int is64, isbf;
        self_detect(nullptr, (const u32*)xraw, is64, isbf);
        if (t < 642) {
            float v;
            if (t < 128) v = load_f(b1, isbf, t);
            else if (t < 256) v = load_f(b2, isbf, t - 128);
            else if (t < 384) v = load_f(b3, isbf, t - 256);
            else if (t < 640) v = load_f(Wo, isbf, t - 384);
            else v = load_f(bo, isbf, t - 640);
            smalls[t] = v;
        }
        return;
    }

    // ---- scatter role ----
    int is64, isbf;
    self_detect(ei, nullptr, is64, isbf);
    int cbase = (blk - (cvb + 13)) * CH;
    int cn = E - cbase;
    if (cn > CH) cn = CH;
    lhist[t] = 0;
    __syncthreads();
    int mysrc[4], myb[4], mydl[4];
#pragma unroll
    for (int k = 0; k < 4; ++k) {
        int i = t + k * 1024;
        myb[k] = -1;
        if (i < cn) {
            int e = cbase + i;
            int s, d;
            if (is64) {
                s = (int)((const uint2*)ei)[(size_t)e].x;
                d = (int)((const uint2*)ei)[(size_t)E + e].x;
            } else {
                s = ei[(size_t)e];
                d = ei[(size_t)E + e];
            }
            if ((unsigned)s >= (unsigned)N) s = 0;
            if ((unsigned)d >= (unsigned)N) d = 0;
            mysrc[k] = s;
            mydl[k] = d & 255;
            myb[k] = d >> 8;
            atomicAdd(&lhist[myb[k]], 1);
        }
    }
    __syncthreads();
    int lane = t & 63, wid = t >> 6;
    int v = lhist[t];
    int inc = v;
#pragma unroll
    for (int off = 1; off < 64; off <<= 1) {
        int o = __shfl_up(inc, off);
        if (lane >= off) inc += o;
    }
    if (lane == 63) wsum[wid] = inc;
    __syncthreads();
    int wpre = 0;
    for (int w = 0; w < wid; ++w) wpre += wsum[w];
    int excl = wpre + inc - v;
    loff[t] = excl;
    lcur[t] = excl;
    if (v > 0) gofs[t] = atomicAdd(&gcur[t], v);
    __syncthreads();
#pragma unroll
    for (int k = 0; k < 4; ++k) {
        if (myb[k] >= 0) {
            int pos = atomicAdd(&lcur[myb[k]], 1);
            ebuf[pos] = (u32)mysrc[k] | ((u32)mydl[k] << 24);
            ebkt[pos] = (u16)myb[k];
        }
    }
    __syncthreads();
#pragma unroll
    for (int k = 0; k < 4; ++k) {
        int i = t + k * 1024;
        if (i < cn) {
            int bb = ebkt[i];
            int local = gofs[bb] + (i - loff[bb]);
            if (local < CAPB) csrbkt[(size_t)bb * CAPB + local] = ebuf[i];
        }
    }
}

// one block per bucket: counting-sort by dst-low, compact into csr via gtot cursor
__global__ __launch_bounds__(512) void csr_build_kernel(
    const u32* __restrict__ csrbkt, const int* __restrict__ gcur,
    int N, int* __restrict__ gtot,
    int* __restrict__ offs, int* __restrict__ cnt,
    int* __restrict__ csr) {
    __shared__ int lh[256], lcur[256], wsum[4];
    __shared__ int sbase;
    __shared__ u32 sbuf[CAPB];
    int t = threadIdx.x;  // 512
    int b = blockIdx.x;
    int cb = gcur[b];
    if (cb > CAPB) cb = CAPB;
    const u32* bsrc = csrbkt + (size_t)b * CAPB;
    int d0 = b << 8;
    if (t < 256) lh[t] = 0;
    __syncthreads();
    for (int i = t; i < cb; i += 512) atomicAdd(&lh[bsrc[i] >> 24], 1);
    __syncthreads();
    int lane = t & 63, wid = t >> 6;
    if (t < 256) {
        int v = lh[t];
        int inc = v;
#pragma unroll
        for (int off = 1; off < 64; off <<= 1) {
            int o = __shfl_up(inc, off);
            if (lane >= off) inc += o;
        }
        if (lane == 63) wsum[wid] = inc;
    }
    __syncthreads();
    if (t < 256) {
        int v = lh[t];
        int inc = v;
#pragma unroll
        for (int off = 1; off < 64; off <<= 1) {
            int o = __shfl_up(inc, off);
            if (lane >= off) inc += o;
        }
        int wpre = 0;
        for (int w = 0; w < wid; ++w) wpre += wsum[w];
        int excl = wpre + inc - v;
        lcur[t] = excl;
        int d = d0 + t;
        if (d < N) {
            lh[t] = excl;  // stash excl (reuse lh)
            cnt[d] = v;
        }
    }
    if (t == 0) sbase = atomicAdd(gtot, cb);
    __syncthreads();
    int base = sbase;
    if (t < 256) {
        int d = d0 + t;
        if (d < N) offs[d] = base + lh[t];
    }
    for (int i = t; i < cb; i += 512) {
        u32 e = bsrc[i];
        int pos = atomicAdd(&lcur[e >> 24], 1);
        sbuf[pos] = e & 0xFFFFFFu;
    }
    __syncthreads();
    for (int i = t; i < cb; i += 512) csr[base + i] = (int)sbuf[i];
}

// ---------------- fused layer v2: proven-agg-grid + appended 16-row GEMM ----------------
// Grid/gather structure IDENTICAL to the proven 42.5 µs agg (8*tstride blocks,
// 16 nodes/block, 4 nodes/wave serial, 8-deep unroll) — the R2 failure was
// grid collapse (782 blocks); here TLP is preserved. Appended per block:
//   agg -> LDS [16][68] u32 (4.3 KB) -> barrier ->
//   16-row dual-GEMM: A = [aggL | xcur rows], B = Wcp (16x16 packing),
//   wave w owns col-tiles {2w, 2w+1}; 16 MFMAs/wave (~150 cy, hidden under
//   other blocks' gather latency; MFMA+VMEM pipes co-schedule) ->
//   barrier -> LDS transpose epilogue -> coalesced dwordx4 stores to xnxt.
// Layer 3: in-block head via LDS-atomic reduce, writes out[node] only.
// Reads xcur, writes xnxt (double-buffer) => no in-place race.
__global__ __launch_bounds__(256) void layer_kernel(
    const u32* __restrict__ xcur, u32* __restrict__ xnxt,
    const int* __restrict__ offs, const int* __restrict__ cnt,
    const int* __restrict__ csr,
    const u16* __restrict__ Wcp, const float* __restrict__ biasf,
    int N, int relu, const float* __restrict__ headw,
    const u32* __restrict__ xw, void* __restrict__ outp, int tstride) {
    __shared__ u32 aggL[16][68];
    __shared__ float hsum[16][2];
    int sub = blockIdx.x / tstride;
    int tile = blockIdx.x % tstride;
    int t = threadIdx.x;
    int w = t >> 6;
    int lane = t & 63;
    int nd0b = tile * 128 + sub * 16;
    if (nd0b >= N) return;
    if (t < 32) ((float*)hsum)[t] = 0.f;

    // ---- gather phase (byte-equivalent to proven agg; output -> LDS) ----
    int nd0 = nd0b + w * 4;
    int nd1 = nd0 + 4 < N ? nd0 + 4 : N;
    for (int nd = nd0; nd < nd1; ++nd) {
        int start = offs[nd];
        int num = cnt[nd];
        float a0 = 0.f, a1 = 0.f;
        int i = 0;
        for (; i + 8 <= num; i += 8) {
            int s0 = csr[start + i + 0], s1 = csr[start + i + 1];
            int s2 = csr[start + i + 2], s3 = csr[start + i + 3];
            int s4 = csr[start + i + 4], s5 = csr[start + i + 5];
            int s6 = csr[start + i + 6], s7 = csr[start + i + 7];
            u32 u0 = xcur[(size_t)s0 * 64 + lane];
            u32 u1 = xcur[(size_t)s1 * 64 + lane];
            u32 u2 = xcur[(size_t)s2 * 64 + lane];
            u32 u3 = xcur[(size_t)s3 * 64 + lane];
            u32 u4 = xcur[(size_t)s4 * 64 + lane];
            u32 u5 = xcur[(size_t)s5 * 64 + lane];
            u32 u6 = xcur[(size_t)s6 * 64 + lane];
            u32 u7 = xcur[(size_t)s7 * 64 + lane];
            a0 += lo2f(u0) + lo2f(u1) + lo2f(u2) + lo2f(u3) +
                  lo2f(u4) + lo2f(u5) + lo2f(u6) + lo2f(u7);
            a1 += hi2f(u0) + hi2f(u1) + hi2f(u2) + hi2f(u3) +
                  hi2f(u4) + hi2f(u5) + hi2f(u6) + hi2f(u7);
        }
        for (; i + 4 <= num; i += 4) {
            int s0 = csr[start + i + 0], s1 = csr[start + i + 1];
            int s2 = csr[start + i + 2], s3 = csr[start + i + 3];
            u32 u0 = xcur[(size_t)s0 * 64 + lane];
            u32 u1 = xcur[(size_t)s1 * 64 + lane];
            u32 u2 = xcur[(size_t)s2 * 64 + lane];
            u32 u3 = xcur[(size_t)s3 * 64 + lane];
            a0 += lo2f(u0) + lo2f(u1) + lo2f(u2) + lo2f(u3);
            a1 += hi2f(u0) + hi2f(u1) + hi2f(u2) + hi2f(u3);
        }
        for (; i < num; ++i) {
            u32 u = xcur[(size_t)csr[start + i] * 64 + lane];
            a0 += lo2f(u);
            a1 += hi2f(u);
        }
        float sc = 1.0f / (float)(num > 1 ? num : 1);
        a0 *= sc;
        a1 *= sc;
        aggL[nd - nd0b][lane] = (u32)f2b(a0) | ((u32)f2b(a1) << 16);
    }
    __syncthreads();

    // ---- MFMA phase: 16 rows x 128 cols, K=256 ----
    int r16 = lane & 15;
    int g4 = lane >> 4;
    int noder = nd0b + r16;
    int nodeC = (noder < N) ? noder : (N - 1);
    floatx4 acc0 = 0.0f, acc1 = 0.0f;
    const u16* bbase = Wcp + (size_t)lane * 8 + (size_t)(w * 2) * 512;
#pragma unroll
    for (int s = 0; s < 8; ++s) {
        bf16x8 a;
        if (s < 4) {
            a = *reinterpret_cast<const bf16x8*>(&aggL[r16][s * 16 + g4 * 4]);
        } else {
            a = *reinterpret_cast<const bf16x8*>(
                xcur + (size_t)nodeC * 64 + (s - 4) * 16 + g4 * 4);
        }
        const u16* bp = bbase + (size_t)(s * 8) * 512;
        bf16x8 b0 = *reinterpret_cast<const bf16x8*>(bp);
        bf16x8 b1 = *reinterpret_cast<const bf16x8*>(bp + 512);
        acc0 = __builtin_amdgcn_mfma_f32_16x16x32_bf16(a, b0, acc0, 0, 0, 0);
        acc1 = __builtin_amdgcn_mfma_f32_16x16x32_bf16(a, b1, acc1, 0, 0, 0);
    }
    __syncthreads();  // A-reads done (aggL reusable); hsum-zero visible

    // C/D: col = lane&15 (+tile base), row = (lane>>4)*4 + r  [verified m89/m91]
    if (outp == nullptr) {
        u16* ldsO = (u16*)aggL;  // [16][136] u16 view
        int col0 = w * 32 + r16;
        float bf0 = biasf[col0], bf1 = biasf[col0 + 16];
#pragma unroll
        for (int r = 0; r < 4; ++r) {
            int row = g4 * 4 + r;
            float v0 = acc0[r] + bf0;
            float v1 = acc1[r] + bf1;
            if (relu) { v0 = fmaxf(v0, 0.0f); v1 = fmaxf(v1, 0.0f); }
            ldsO[row * 136 + col0] = f2b(v0);
            ldsO[row * 136 + col0 + 16] = f2b(v1);
        }
        __syncthreads();
        int row = t >> 4, seg = t & 15;
        int nodeS = nd0b + row;
        if (nodeS < N) {
            const u16* lp = ldsO + row * 136 + seg * 8;
            uint2 lo = *reinterpret_cast<const uint2*>(lp);
            uint2 hi = *reinterpret_cast<const uint2*>(lp + 4);
            u32x4 o;
            o.x = lo.x; o.y = lo.y; o.z = hi.x; o.w = hi.y;
            *reinterpret_cast<u32x4*>(&xnxt[(size_t)nodeS * 64 + seg * 4]) = o;
        }
    } else {
        // fused head: h = acc + bl3; out = (h.Wo0 + bo0, h.Wo1 + bo1)
        int is64, isbf;
        self_detect(nullptr, xw, is64, isbf);  // full wave active
        int col0 = w * 32 + r16;
        int col1 = col0 + 16;
        float bf0 = biasf[col0], bf1 = biasf[col1];
        float w00 = headw[col0], w01 = headw[col1];
        float w10 = headw[128 + col0], w11 = headw[128 + col1];
#pragma unroll
        for (int r = 0; r < 4; ++r) {
            float h0 = acc0[r] + bf0;
            float h1 = acc1[r] + bf1;
            float p0 = h0 * w00 + h1 * w01;
            float p1 = h0 * w10 + h1 * w11;
#pragma unroll
            for (int off = 8; off > 0; off >>= 1) {
                p0 += __shfl_xor(p0, off);
                p1 += __shfl_xor(p1, off);
            }
            if (r16 == 0) {
                atomicAdd(&hsum[g4 * 4 + r][0], p0);
                atomicAdd(&hsum[g4 * 4 + r][1], p1);
            }
        }
        __syncthreads();
        if (t < 16) {
            int nodeS = nd0b + t;
            if (nodeS < N) {
                float o0 = hsum[t][0] + headw[256];  // bo0
                float o1 = hsum[t][1] + headw[257];  // bo1
                if (isbf)
                    ((u32*)outp)[nodeS] = (u32)f2b(o0) | ((u32)f2b(o1) << 16);
                else
                    ((float2*)outp)[nodeS] = make_float2(o0, o1);
            }
        }
    }
}

extern "C" void kernel_launch(void* const* d_in, const int* in_sizes, int n_in,
                              void* d_out, int out_size, void* d_ws, size_t ws_size,
                              hipStream_t stream) {
    const int N = in_sizes[0] / 128;
    const int E = in_sizes[1] / 2;

    const void* x = d_in[0];
    const int* ei = (const int*)d_in[1];
    const void* Wl[3] = {d_in[2], d_in[5], d_in[8]};
    const void* bl[3] = {d_in[3], d_in[6], d_in[9]};
    const void* Wr[3] = {d_in[4], d_in[7], d_in[10]};
    const void* Wo = d_in[11];
    const void* bo = d_in[12];

    // workspace bump allocator (256B aligned)
    char* p = (char*)d_ws;
    auto alloc = [&](size_t bytes) -> char* {
        char* r = p;
        p += (bytes + 255) & ~(size_t)255;
        return r;
    };
    int* offs = (int*)alloc((size_t)N * 4);
    int* cnt = (int*)alloc((size_t)N * 4);
    float* smalls = (float*)alloc(642 * 4);
    int* gcur = (int*)alloc(1025 * 4);  // [1024] = gtot
    int* csr = (int*)alloc(((size_t)E + CAPB + 64) * 4);  // over-alloc: padded reads safe
    u16* Wcp = (u16*)alloc((size_t)3 * 4096 * 8 * 2);
    u32* x0 = (u32*)alloc((size_t)(N + 1) * 64 * 4);
    u32* x1 = (u32*)alloc((size_t)(N + 1) * 64 * 4);  // aliased as csrbkt during build
    u32* csrbkt = x1;                                  // dead until layers start
    int* gtot = gcur + 1024;
    (void)ws_size;

    const int NB = (N + 255) / 256;          // buckets
    const int cvb = (N * 16 + 1023) / 1024;  // convert blocks (1024 thr)
    const int sb = (E + CH - 1) / CH;        // scatter blocks
    const int gb = (N + 127) / 128;          // tiles (128 nodes)
    const int tstride = (gb + 7) & ~7;       // tile stride, mult of 8 (XCD affinity)
    const int ab = 8 * tstride;              // layer blocks: 8 sub-blocks x tstride tiles

    hipMemsetAsync(gcur, 0, 1025 * 4, stream);
    front_kernel<<<cvb + 13 + sb, 1024, 0, stream>>>(
        x, ei, E, N, cvb, x0, gcur, csrbkt,
        Wl[0], Wr[0], Wl[1], Wr[1], Wl[2], Wr[2],
        bl[0], bl[1], bl[2], Wo, bo, Wcp, smalls);
    csr_build_kernel<<<NB, 512, 0, stream>>>(csrbkt, gcur, N, gtot, offs, cnt, csr);

    // layer 1: x0 -> x1
    layer_kernel<<<ab, 256, 0, stream>>>(x0, x1, offs, cnt, csr, Wcp, smalls, N, 1,
                                         nullptr, nullptr, nullptr, tstride);
    // layer 2: x1 -> x0
    layer_kernel<<<ab, 256, 0, stream>>>(x1, x0, offs, cnt, csr, Wcp + 32768, smalls + 128, N, 1,
                                         nullptr, nullptr, nullptr, tstride);
    // layer 3 + fused head: x0 -> d_out
    layer_kernel<<<ab, 256, 0, stream>>>(x0, x1, offs, cnt, csr, Wcp + 65536, smalls + 256, N, 0,
                                         smalls + 384, (const u32*)x, d_out, tstride);
}